// Round 6
// baseline (6197.691 us; speedup 1.0000x reference)
//
#include <hip/hip_runtime.h>

// SimpleLSTM B=64, T=2048, H=512. Round 12: R0 skeleton + padded counters +
// per-wave producer-subset poll (B1 barrier removed).
// Sync medium UNCHANGED from the proven R0 kernel: counters are sc1/MALL both
// directions (R9/R11 proved plain-L2 flags cannot be ordered vs plain data
// stores from the producer side); h-ring data is plain-store + sc0-load in
// XCD L2 (probe-gated FAST) with the R0-proven {vmcnt-drain -> B3 -> sc1
// bump} release. New in R12:
//  (a) counters padded to 64B each (32 MALL lines/group, parallel bank
//      service instead of ~2048 same-line spins on 2 lines),
//  (b) wave wid polls only its 8 producer blocks (K-slice [128wid,128wid+128)
//      = blocks 8wid..8wid+7) with 8 lanes, then goes straight to A-load +
//      MFMA — no block-wide B1 syncthreads. B2 still implies the group-wide
//      >=t certificate (union of 4 waves' subsets) for epilogue/ring safety.
// 8 groups x 8 batches x 32 blocks, 64 rows/block, W hi/lo bf16 in VGPRs.
// Fallback: sc1 data everywhere (R3-proven), same new poll topology.

#define TT 2048
#define BB 64
#define HH 512
#define GB 8            // batches per group
#define NBLK 32         // blocks per group
#define DEPTH 4
#define PLANE (GB * HH) // 4096 bf16 per plane-slot (8 KB)
#define CPAD 16         // uints per counter (64B line each)
#define Y_OFF 0
#define HN_OFF (BB * TT)
#define CN_OFF (BB * TT + BB * HH)

typedef short short8 __attribute__((ext_vector_type(8)));
typedef float f32x4  __attribute__((ext_vector_type(4)));

__device__ __forceinline__ unsigned f2bf(float f) {  // RNE fp32->bf16 bits
    unsigned u = __float_as_uint(f);
    return (u + 0x7fffu + ((u >> 16) & 1u)) >> 16;
}
__device__ __forceinline__ float bf2f(unsigned h) { return __uint_as_float(h << 16); }

// ---- relaxed agent-scope (sc1/MALL) primitives — R3-proven ----------------
__device__ __forceinline__ unsigned ld_agent(const unsigned* p) {
    return __hip_atomic_load(p, __ATOMIC_RELAXED, __HIP_MEMORY_SCOPE_AGENT);
}
__device__ __forceinline__ void st_agent(unsigned* p, unsigned v) {
    __hip_atomic_store(p, v, __ATOMIC_RELAXED, __HIP_MEMORY_SCOPE_AGENT);
}
__device__ __forceinline__ unsigned add_agent(unsigned* p, unsigned v) {
    return __hip_atomic_fetch_add(p, v, __ATOMIC_RELAXED, __HIP_MEMORY_SCOPE_AGENT);
}
__device__ __forceinline__ short8 ld_sc1_b128(const unsigned short* p) {
    unsigned long long q0 = __hip_atomic_load((const unsigned long long*)p,
                                              __ATOMIC_RELAXED, __HIP_MEMORY_SCOPE_AGENT);
    unsigned long long q1 = __hip_atomic_load((const unsigned long long*)(p + 4),
                                              __ATOMIC_RELAXED, __HIP_MEMORY_SCOPE_AGENT);
    union { unsigned long long q[2]; short8 s; } u;
    u.q[0] = q0; u.q[1] = q1;
    return u.s;
}

// ---- sc0 (L1-bypass, XCD-L2) data loads: FAST path only, probe-gated ------
__device__ __forceinline__ void ld_sc0_8x128(const void* pa, const void* pb,
                                             short8* A, short8* B) {
    asm volatile(
        "global_load_dwordx4 %0, %[pa], off sc0\n\t"
        "global_load_dwordx4 %1, %[pa], off offset:64 sc0\n\t"
        "global_load_dwordx4 %2, %[pa], off offset:128 sc0\n\t"
        "global_load_dwordx4 %3, %[pa], off offset:192 sc0\n\t"
        "global_load_dwordx4 %4, %[pb], off sc0\n\t"
        "global_load_dwordx4 %5, %[pb], off offset:64 sc0\n\t"
        "global_load_dwordx4 %6, %[pb], off offset:128 sc0\n\t"
        "global_load_dwordx4 %7, %[pb], off offset:192 sc0\n\t"
        "s_waitcnt vmcnt(0)"
        : "=&v"(A[0]), "=&v"(A[1]), "=&v"(A[2]), "=&v"(A[3]),
          "=&v"(B[0]), "=&v"(B[1]), "=&v"(B[2]), "=&v"(B[3])
        : [pa] "v"(pa), [pb] "v"(pb)
        : "memory");
}
__device__ __forceinline__ uint4 ld_sc0_probe(const void* p) {
    uint4 d;
    asm volatile("global_load_dwordx4 %0, %1, off sc0\n\ts_waitcnt vmcnt(0)"
                 : "=&v"(d) : "v"(p) : "memory");
    return d;
}

#define GSP(w, tl, r, c) gsp[((((w) * 4 + (tl)) * 16 + (r)) * 20) + (c)]

template <bool FAST>
__device__ __noinline__ void run_loop(
    const float* __restrict__ x, const float* __restrict__ Whh,
    const float* __restrict__ Wih, const float* __restrict__ bih,
    const float* __restrict__ bhh, const float* __restrict__ Wfc,
    const float* __restrict__ bfc, float* __restrict__ out,
    unsigned short* __restrict__ hb, unsigned* __restrict__ stepc,
    const int grp, const int ut, float* gsp)
{
    const int tid  = threadIdx.x;
    const int wid  = tid >> 6;          // wave 0..3 -> K-slice wid*128..+128
    const int lane = tid & 63;
    const int quad = lane >> 4;
    const int l16  = lane & 15;

    // ---- persistent W fragments (hi/lo split); tile tl = gate, 16 units ----
    short8 whi[4][4], wlo[4][4];
#pragma unroll
    for (int tl = 0; tl < 4; ++tl) {
        const int grow  = tl * HH + ut * 16 + l16;   // row = gate*512 + unit
        const float* wr = Whh + grow * HH + wid * 128 + quad * 8;
#pragma unroll
        for (int ki = 0; ki < 4; ++ki) {
            const float* wp = wr + ki * 32;
            short8 h8, l8;
#pragma unroll
            for (int j = 0; j < 8; ++j) {
                const float f = wp[j];
                const unsigned hi = f2bf(f);
                h8[j] = (short)hi;
                l8[j] = (short)f2bf(f - bf2f(hi));
            }
            whi[tl][ki] = h8;
            wlo[tl][ki] = l8;
        }
    }

    // ---- epilogue role (tid < 128): batch b2, unit u ----
    const int b2    = (tid >> 4) & 7;
    const int u     = tid & 15;
    const int bglob = grp * GB + b2;
    const int ug    = ut * 16 + u;
    float wih4[4], bia4[4];
#pragma unroll
    for (int gi = 0; gi < 4; ++gi) {
        const int grow = gi * HH + ug;
        wih4[gi] = Wih[grow];
        bia4[gi] = bih[grow] + bhh[grow];
    }
    const float wfc  = Wfc[ug];
    const float bfcv = bfc[0];
    float c = 0.0f;

    const int base_hi = grp * 2 * DEPTH;
    const int base_lo = base_hi + DEPTH;
    unsigned* hb32 = (unsigned*)hb;

    // Per-wave producer poll target: wave wid's A K-slice [128wid,128wid+128)
    // is produced by blocks 8wid..8wid+7 (block b owns units [16b,16b+16)).
    // Lane i<8 polls padded counter (8*wid+i); lanes 8..63 auto-true.
    const unsigned* pollp = stepc + (unsigned)((wid * 8 + (lane & 7)) * CPAD);

    // Poll fuse: global spin budget across all steps; a livelock becomes a
    // visible wrong-answer failure instead of a container hang.
    int fuse = 1 << 24;

    for (int t = 0; t < TT; ++t) {
        // x is read-only — load before the poll so its latency overlaps waiting
        const float xv = x[bglob * TT + t];

        // ---- B1 (per-wave, no barrier): wait for THIS wave's 8 producers.
        // counter[b] >= t  <=>  block b finished step t-1 entirely (B3 of
        // t-1 passed: h(t) stores vmcnt-drained before the sc1 bump).
        {
            const unsigned tgt = (unsigned)t;
            for (;;) {
                unsigned v = 0xFFFFFFFFu;
                if (lane < 8) v = ld_agent(pollp);   // sc1: proven medium
                if (__all((int)(v >= tgt))) break;
                if (--fuse <= 0) break;              // hang fuse
            }
        }

        // ---- A = H[8(dup16) x 512] from ring slot t&3, this wave's K-slice ----
        const unsigned short* Ah =
            hb + (base_hi + (t & 3)) * PLANE + (l16 & 7) * HH + wid * 128 + quad * 8;
        const unsigned short* Al =
            hb + (base_lo + (t & 3)) * PLANE + (l16 & 7) * HH + wid * 128 + quad * 8;
        short8 ah[4], al[4];
        if constexpr (FAST) {
            ld_sc0_8x128(Ah, Al, ah, al);   // XCD-L2 local, L1-bypassed
        } else {
#pragma unroll
            for (int ki = 0; ki < 4; ++ki) {
                ah[ki] = ld_sc1_b128(Ah + ki * 32);
                al[ki] = ld_sc1_b128(Al + ki * 32);
            }
        }

        f32x4 acc[4] = {{0.f,0.f,0.f,0.f},{0.f,0.f,0.f,0.f},
                        {0.f,0.f,0.f,0.f},{0.f,0.f,0.f,0.f}};
#pragma unroll
        for (int ki = 0; ki < 4; ++ki) {
#pragma unroll
            for (int tl = 0; tl < 4; ++tl)
                acc[tl] = __builtin_amdgcn_mfma_f32_16x16x32_bf16(ah[ki], whi[tl][ki], acc[tl], 0, 0, 0);
#pragma unroll
            for (int tl = 0; tl < 4; ++tl)
                acc[tl] = __builtin_amdgcn_mfma_f32_16x16x32_bf16(al[ki], whi[tl][ki], acc[tl], 0, 0, 0);
#pragma unroll
            for (int tl = 0; tl < 4; ++tl)
                acc[tl] = __builtin_amdgcn_mfma_f32_16x16x32_bf16(ah[ki], wlo[tl][ki], acc[tl], 0, 0, 0);
        }
        // D: col=lane&15 (unit), row=quad*4+reg (batch; rows 8..15 are dups)
#pragma unroll
        for (int tl = 0; tl < 4; ++tl)
#pragma unroll
            for (int r = 0; r < 4; ++r)
                GSP(wid, tl, quad * 4 + r, l16) = acc[tl][r];
        __syncthreads();  // B2: gsp exchange; implies all 32 producers >= t

        if (tid < 128) {
            float pre[4];
#pragma unroll
            for (int gi = 0; gi < 4; ++gi) {
                float s = 0.f;
#pragma unroll
                for (int w = 0; w < 4; ++w) s += GSP(w, gi, b2, u);
                pre[gi] = fmaf(xv, wih4[gi], bia4[gi]) + s;
            }
            const float ig = 1.f / (1.f + __expf(-pre[0]));
            const float fg = 1.f / (1.f + __expf(-pre[1]));
            const float gg = 2.f / (1.f + __expf(-2.f * pre[2])) - 1.f;
            const float og = 1.f / (1.f + __expf(-pre[3]));
            c = fmaf(fg, c, ig * gg);
            const float tc = 2.f / (1.f + __expf(-2.f * c)) - 1.f;
            const float h  = og * tc;

            // ---- h -> ring slot (t+1)&3, hi/lo planes, paired dword stores ----
            // (overwrites h(t-3): safe, B2's group-wide >=t certificate means
            // every block finished step t-1 >= its read of slot (t-3)&3)
            const unsigned hh = f2bf(h);
            const unsigned hl = f2bf(h - bf2f(hh));
            const unsigned packed = hh | (hl << 16);
            const unsigned part = (unsigned)__shfl_xor((int)packed, 1, 64);
            if ((u & 1) == 0) {
                const unsigned sH = __builtin_amdgcn_perm(part, packed, 0x05040100u);
                const unsigned sL = __builtin_amdgcn_perm(part, packed, 0x07060302u);
                const int slot    = (t + 1) & 3;
                const int pairidx = (b2 * HH + ug) >> 1;
                if constexpr (FAST) {  // plain write-through -> XCD L2 (probed)
                    __hip_atomic_store(hb32 + (base_hi + slot) * (PLANE / 2) + pairidx, sH,
                                       __ATOMIC_RELAXED, __HIP_MEMORY_SCOPE_WORKGROUP);
                    __hip_atomic_store(hb32 + (base_lo + slot) * (PLANE / 2) + pairidx, sL,
                                       __ATOMIC_RELAXED, __HIP_MEMORY_SCOPE_WORKGROUP);
                } else {
                    __hip_atomic_store(hb32 + (base_hi + slot) * (PLANE / 2) + pairidx, sH,
                                       __ATOMIC_RELAXED, __HIP_MEMORY_SCOPE_AGENT);
                    __hip_atomic_store(hb32 + (base_lo + slot) * (PLANE / 2) + pairidx, sL,
                                       __ATOMIC_RELAXED, __HIP_MEMORY_SCOPE_AGENT);
                }
            }

            // y[b][t]: reduce 16 units, one atomic per (block, batch)
            float yp = h * wfc;
            yp += __shfl_down(yp, 8, 16);
            yp += __shfl_down(yp, 4, 16);
            yp += __shfl_down(yp, 2, 16);
            yp += __shfl_down(yp, 1, 16);
            if (u == 0) {
                if (ut == 0) yp += bfcv;
                if constexpr (FAST)  // L2-local add; line is group-exclusive
                    __hip_atomic_fetch_add(out + Y_OFF + bglob * TT + t, yp,
                                           __ATOMIC_RELAXED, __HIP_MEMORY_SCOPE_WORKGROUP);
                else
                    atomicAdd(out + Y_OFF + bglob * TT + t, yp);
            }
            if (t == TT - 1) {
                out[HN_OFF + bglob * HH + ug] = h;
                out[CN_OFF + bglob * HH + ug] = c;
            }
        }
        // B3: compiler emits s_waitcnt vmcnt(0) before s_barrier -> all h
        // stores are in L2 (FAST) / MALL (SLOW) before the counter bump.
        // Also fences GSP reuse (next step's per-wave writes) against this
        // step's epilogue reads. R0-proven release: drain -> barrier -> sc1.
        __syncthreads();
        if (tid == 0) st_agent(stepc + ut * CPAD, (unsigned)(t + 1));  // sc1 always
    }
}

__global__ __launch_bounds__(256, 1)
void lstm_xcd(const float* __restrict__ x, const float* __restrict__ Wih,
              const float* __restrict__ Whh, const float* __restrict__ bih,
              const float* __restrict__ bhh, const float* __restrict__ Wfc,
              const float* __restrict__ bfc, float* __restrict__ out,
              unsigned short* __restrict__ hb, unsigned* __restrict__ cnt)
{
    __shared__ int s_grp, s_ut, s_fast;
    __shared__ float gsp[4 * 4 * 16 * 20];  // 20 KB cross-wave partial-C

    const int tid = threadIdx.x;
    // cnt layout (uints, 32 KB): [0,4096) padded stepc (grp*512 + blk*16,
    // 64B per counter); [4096,4104) claim; [4136] bar1; probe data
    // 4608+g*32 (uint4); pflag 4864+g*32; v_ok 5120+g*32; v_tot 5376+g*32
    unsigned* claim = cnt + 4096;
    unsigned* bar1  = cnt + 4136;

    if (tid == 0) {
        unsigned xcc;
        asm volatile("s_getreg_b32 %0, hwreg(HW_REG_XCC_ID)" : "=s"(xcc));
        xcc &= 7u;
        const unsigned slot = add_agent(claim + xcc, 1u);
        asm volatile("s_waitcnt vmcnt(0)" ::: "memory");
        add_agent(bar1, 1u);
        while (ld_agent(bar1) < 256u) __builtin_amdgcn_s_sleep(1);
        bool pure = true;
        for (int g2 = 0; g2 < 8; ++g2) pure &= (ld_agent(claim + g2) == (unsigned)NBLK);

        int fast = 0, grp, ut;
        if (pure) {
            grp = (int)xcc; ut = (int)slot;
            // ---- coherence probe of the FAST data mechanism (all waits
            // terminate: pflag set unconditionally by ut0; votes reach 32
            // unconditionally)
            unsigned* probe = cnt + 4608 + grp * 32;
            unsigned* pflag = cnt + 4864 + grp * 32;
            unsigned* v_ok  = cnt + 5120 + grp * 32;
            unsigned* v_tot = cnt + 5376 + grp * 32;
            if (ut == 0) {
                uint4 m = make_uint4(0xC0FFEE42u, 0x5EED5EEDu, 0xA110C8EDu, 0xB16B00B5u);
                *(uint4*)probe = m;                      // plain write-through store
                asm volatile("s_waitcnt vmcnt(0)" ::: "memory");
                st_agent(pflag, 1u);
            }
            while (ld_agent(pflag) == 0u) __builtin_amdgcn_s_sleep(1);
            const uint4 d = ld_sc0_probe(probe);         // the FAST load path
            const unsigned ok = (d.x == 0xC0FFEE42u && d.y == 0x5EED5EEDu &&
                                 d.z == 0xA110C8EDu && d.w == 0xB16B00B5u) ? 1u : 0u;
            add_agent(v_ok, ok);
            asm volatile("s_waitcnt vmcnt(0)" ::: "memory");  // ok before total
            add_agent(v_tot, 1u);
            while (ld_agent(v_tot) < (unsigned)NBLK) __builtin_amdgcn_s_sleep(1);
            fast = (ld_agent(v_ok) == (unsigned)NBLK) ? 1 : 0;
        } else {
            grp = (int)(blockIdx.x >> 5); ut = (int)(blockIdx.x & 31);
        }
        s_grp = grp; s_ut = ut; s_fast = fast;
    }
    __syncthreads();
    const int grp = s_grp, ut = s_ut;
    unsigned* stepc = cnt + grp * (NBLK * CPAD);

    if (s_fast) run_loop<true >(x, Whh, Wih, bih, bhh, Wfc, bfc, out, hb, stepc, grp, ut, gsp);
    else        run_loop<false>(x, Whh, Wih, bih, bhh, Wfc, bfc, out, hb, stepc, grp, ut, gsp);
}

extern "C" void kernel_launch(void* const* d_in, const int* in_sizes, int n_in,
                              void* d_out, int out_size, void* d_ws, size_t ws_size,
                              hipStream_t stream) {
    const float* x   = (const float*)d_in[0];
    const float* Wih = (const float*)d_in[1];
    const float* Whh = (const float*)d_in[2];
    const float* bih = (const float*)d_in[3];
    const float* bhh = (const float*)d_in[4];
    const float* Wfc = (const float*)d_in[5];
    const float* bfc = (const float*)d_in[6];
    float* out = (float*)d_out;

    // ws: [0,32K) counters/claims/probe (padded); [32K, 32K+512K) h ring
    unsigned*       cnt = (unsigned*)d_ws;
    unsigned short* hb  = (unsigned short*)((char*)d_ws + 32768);

    hipMemsetAsync(d_ws, 0, 32768 + 8 * 2 * DEPTH * PLANE * sizeof(unsigned short), stream);
    hipMemsetAsync(d_out, 0, BB * TT * sizeof(float), stream);  // atomic target

    lstm_xcd<<<dim3(256), dim3(256), 0, stream>>>(
        x, Wih, Whh, bih, bhh, Wfc, bfc, out, hb, cnt);
}

// Round 7
// 5547.504 us; speedup vs baseline: 1.1172x; 1.1172x over previous
//
#include <hip/hip_runtime.h>

// SimpleLSTM B=64, T=2048, H=512. Round 13: R12 steady path untouched +
// de-fanged SLOW fallback.
// R12 profile: steady FAST dispatches 5585us (-7.3% vs R0) but ~3% of
// launches are XCD-impure -> SLOW at ~26ms, dragging the headline. SLOW was
// 26ms because its A-loads were 8B __hip_atomic_loads (compiler serializes
// each -> ~16 MALL RTs/step) and 8192 unthrottled poll streams hammered the
// MALL. R13: SLOW A-load = 8x global_load_dwordx4 sc0 sc1 issued in
// PARALLEL + one vmcnt (same MALL-coherent medium, parallel issue); SLOW
// poll miss throttled with s_sleep(1). FAST path byte-identical to R12:
//  (a) counters padded to 64B each (32 MALL lines/group),
//  (b) per-wave producer-subset poll (8 producers/wave), no B1 barrier,
//  (c) h-ring plain-store + sc0-load in XCD L2 (probe-gated), R0-proven
//      {vmcnt-drain -> B3 -> sc1 bump} release; counters sc1/MALL always
//      (R9/R11: plain-L2 flags cannot be ordered vs plain data stores).
// 8 groups x 8 batches x 32 blocks, 64 rows/block, W hi/lo bf16 in VGPRs.

#define TT 2048
#define BB 64
#define HH 512
#define GB 8            // batches per group
#define NBLK 32         // blocks per group
#define DEPTH 4
#define PLANE (GB * HH) // 4096 bf16 per plane-slot (8 KB)
#define CPAD 16         // uints per counter (64B line each)
#define Y_OFF 0
#define HN_OFF (BB * TT)
#define CN_OFF (BB * TT + BB * HH)

typedef short short8 __attribute__((ext_vector_type(8)));
typedef float f32x4  __attribute__((ext_vector_type(4)));

__device__ __forceinline__ unsigned f2bf(float f) {  // RNE fp32->bf16 bits
    unsigned u = __float_as_uint(f);
    return (u + 0x7fffu + ((u >> 16) & 1u)) >> 16;
}
__device__ __forceinline__ float bf2f(unsigned h) { return __uint_as_float(h << 16); }

// ---- relaxed agent-scope (sc1/MALL) primitives — R3-proven ----------------
__device__ __forceinline__ unsigned ld_agent(const unsigned* p) {
    return __hip_atomic_load(p, __ATOMIC_RELAXED, __HIP_MEMORY_SCOPE_AGENT);
}
__device__ __forceinline__ void st_agent(unsigned* p, unsigned v) {
    __hip_atomic_store(p, v, __ATOMIC_RELAXED, __HIP_MEMORY_SCOPE_AGENT);
}
__device__ __forceinline__ unsigned add_agent(unsigned* p, unsigned v) {
    return __hip_atomic_fetch_add(p, v, __ATOMIC_RELAXED, __HIP_MEMORY_SCOPE_AGENT);
}

// ---- sc0 (L1-bypass, XCD-L2) data loads: FAST path, probe-gated -----------
__device__ __forceinline__ void ld_sc0_8x128(const void* pa, const void* pb,
                                             short8* A, short8* B) {
    asm volatile(
        "global_load_dwordx4 %0, %[pa], off sc0\n\t"
        "global_load_dwordx4 %1, %[pa], off offset:64 sc0\n\t"
        "global_load_dwordx4 %2, %[pa], off offset:128 sc0\n\t"
        "global_load_dwordx4 %3, %[pa], off offset:192 sc0\n\t"
        "global_load_dwordx4 %4, %[pb], off sc0\n\t"
        "global_load_dwordx4 %5, %[pb], off offset:64 sc0\n\t"
        "global_load_dwordx4 %6, %[pb], off offset:128 sc0\n\t"
        "global_load_dwordx4 %7, %[pb], off offset:192 sc0\n\t"
        "s_waitcnt vmcnt(0)"
        : "=&v"(A[0]), "=&v"(A[1]), "=&v"(A[2]), "=&v"(A[3]),
          "=&v"(B[0]), "=&v"(B[1]), "=&v"(B[2]), "=&v"(B[3])
        : [pa] "v"(pa), [pb] "v"(pb)
        : "memory");
}
// ---- sc0 sc1 (L1+L2 bypass, MALL-coherent) loads: SLOW path ---------------
// Same medium as the R3-proven sc1 atomic loads, but 8x16B issued in
// PARALLEL with a single vmcnt wait (~1 MALL RT instead of ~16 serialized).
__device__ __forceinline__ void ld_mall_8x128(const void* pa, const void* pb,
                                              short8* A, short8* B) {
    asm volatile(
        "global_load_dwordx4 %0, %[pa], off sc0 sc1\n\t"
        "global_load_dwordx4 %1, %[pa], off offset:64 sc0 sc1\n\t"
        "global_load_dwordx4 %2, %[pa], off offset:128 sc0 sc1\n\t"
        "global_load_dwordx4 %3, %[pa], off offset:192 sc0 sc1\n\t"
        "global_load_dwordx4 %4, %[pb], off sc0 sc1\n\t"
        "global_load_dwordx4 %5, %[pb], off offset:64 sc0 sc1\n\t"
        "global_load_dwordx4 %6, %[pb], off offset:128 sc0 sc1\n\t"
        "global_load_dwordx4 %7, %[pb], off offset:192 sc0 sc1\n\t"
        "s_waitcnt vmcnt(0)"
        : "=&v"(A[0]), "=&v"(A[1]), "=&v"(A[2]), "=&v"(A[3]),
          "=&v"(B[0]), "=&v"(B[1]), "=&v"(B[2]), "=&v"(B[3])
        : [pa] "v"(pa), [pb] "v"(pb)
        : "memory");
}
__device__ __forceinline__ uint4 ld_sc0_probe(const void* p) {
    uint4 d;
    asm volatile("global_load_dwordx4 %0, %1, off sc0\n\ts_waitcnt vmcnt(0)"
                 : "=&v"(d) : "v"(p) : "memory");
    return d;
}

#define GSP(w, tl, r, c) gsp[((((w) * 4 + (tl)) * 16 + (r)) * 20) + (c)]

template <bool FAST>
__device__ __noinline__ void run_loop(
    const float* __restrict__ x, const float* __restrict__ Whh,
    const float* __restrict__ Wih, const float* __restrict__ bih,
    const float* __restrict__ bhh, const float* __restrict__ Wfc,
    const float* __restrict__ bfc, float* __restrict__ out,
    unsigned short* __restrict__ hb, unsigned* __restrict__ stepc,
    const int grp, const int ut, float* gsp)
{
    const int tid  = threadIdx.x;
    const int wid  = tid >> 6;          // wave 0..3 -> K-slice wid*128..+128
    const int lane = tid & 63;
    const int quad = lane >> 4;
    const int l16  = lane & 15;

    // ---- persistent W fragments (hi/lo split); tile tl = gate, 16 units ----
    short8 whi[4][4], wlo[4][4];
#pragma unroll
    for (int tl = 0; tl < 4; ++tl) {
        const int grow  = tl * HH + ut * 16 + l16;   // row = gate*512 + unit
        const float* wr = Whh + grow * HH + wid * 128 + quad * 8;
#pragma unroll
        for (int ki = 0; ki < 4; ++ki) {
            const float* wp = wr + ki * 32;
            short8 h8, l8;
#pragma unroll
            for (int j = 0; j < 8; ++j) {
                const float f = wp[j];
                const unsigned hi = f2bf(f);
                h8[j] = (short)hi;
                l8[j] = (short)f2bf(f - bf2f(hi));
            }
            whi[tl][ki] = h8;
            wlo[tl][ki] = l8;
        }
    }

    // ---- epilogue role (tid < 128): batch b2, unit u ----
    const int b2    = (tid >> 4) & 7;
    const int u     = tid & 15;
    const int bglob = grp * GB + b2;
    const int ug    = ut * 16 + u;
    float wih4[4], bia4[4];
#pragma unroll
    for (int gi = 0; gi < 4; ++gi) {
        const int grow = gi * HH + ug;
        wih4[gi] = Wih[grow];
        bia4[gi] = bih[grow] + bhh[grow];
    }
    const float wfc  = Wfc[ug];
    const float bfcv = bfc[0];
    float c = 0.0f;

    const int base_hi = grp * 2 * DEPTH;
    const int base_lo = base_hi + DEPTH;
    unsigned* hb32 = (unsigned*)hb;

    // Per-wave producer poll target: wave wid's A K-slice [128wid,128wid+128)
    // is produced by blocks 8wid..8wid+7 (block b owns units [16b,16b+16)).
    // Lane i<8 polls padded counter (8*wid+i); lanes 8..63 auto-true.
    const unsigned* pollp = stepc + (unsigned)((wid * 8 + (lane & 7)) * CPAD);

    // Poll fuse: global spin budget across all steps; a livelock becomes a
    // visible wrong-answer failure instead of a container hang.
    int fuse = 1 << 24;

    for (int t = 0; t < TT; ++t) {
        // x is read-only — load before the poll so its latency overlaps waiting
        const float xv = x[bglob * TT + t];

        // ---- B1 (per-wave, no barrier): wait for THIS wave's 8 producers.
        // counter[b] >= t  <=>  block b finished step t-1 entirely (B3 of
        // t-1 passed: h(t) stores vmcnt-drained before the sc1 bump).
        {
            const unsigned tgt = (unsigned)t;
            for (;;) {
                unsigned v = 0xFFFFFFFFu;
                if (lane < 8) v = ld_agent(pollp);   // sc1: proven medium
                if (__all((int)(v >= tgt))) break;
                if (--fuse <= 0) break;              // hang fuse
                if constexpr (!FAST)                 // throttle MALL pressure
                    __builtin_amdgcn_s_sleep(1);
            }
        }

        // ---- A = H[8(dup16) x 512] from ring slot t&3, this wave's K-slice ----
        const unsigned short* Ah =
            hb + (base_hi + (t & 3)) * PLANE + (l16 & 7) * HH + wid * 128 + quad * 8;
        const unsigned short* Al =
            hb + (base_lo + (t & 3)) * PLANE + (l16 & 7) * HH + wid * 128 + quad * 8;
        short8 ah[4], al[4];
        if constexpr (FAST) {
            ld_sc0_8x128(Ah, Al, ah, al);   // XCD-L2 local, L1-bypassed
        } else {
            ld_mall_8x128(Ah, Al, ah, al);  // MALL-coherent, parallel issue
        }

        f32x4 acc[4] = {{0.f,0.f,0.f,0.f},{0.f,0.f,0.f,0.f},
                        {0.f,0.f,0.f,0.f},{0.f,0.f,0.f,0.f}};
#pragma unroll
        for (int ki = 0; ki < 4; ++ki) {
#pragma unroll
            for (int tl = 0; tl < 4; ++tl)
                acc[tl] = __builtin_amdgcn_mfma_f32_16x16x32_bf16(ah[ki], whi[tl][ki], acc[tl], 0, 0, 0);
#pragma unroll
            for (int tl = 0; tl < 4; ++tl)
                acc[tl] = __builtin_amdgcn_mfma_f32_16x16x32_bf16(al[ki], whi[tl][ki], acc[tl], 0, 0, 0);
#pragma unroll
            for (int tl = 0; tl < 4; ++tl)
                acc[tl] = __builtin_amdgcn_mfma_f32_16x16x32_bf16(ah[ki], wlo[tl][ki], acc[tl], 0, 0, 0);
        }
        // D: col=lane&15 (unit), row=quad*4+reg (batch; rows 8..15 are dups)
#pragma unroll
        for (int tl = 0; tl < 4; ++tl)
#pragma unroll
            for (int r = 0; r < 4; ++r)
                GSP(wid, tl, quad * 4 + r, l16) = acc[tl][r];
        __syncthreads();  // B2: gsp exchange; implies all 32 producers >= t

        if (tid < 128) {
            float pre[4];
#pragma unroll
            for (int gi = 0; gi < 4; ++gi) {
                float s = 0.f;
#pragma unroll
                for (int w = 0; w < 4; ++w) s += GSP(w, gi, b2, u);
                pre[gi] = fmaf(xv, wih4[gi], bia4[gi]) + s;
            }
            const float ig = 1.f / (1.f + __expf(-pre[0]));
            const float fg = 1.f / (1.f + __expf(-pre[1]));
            const float gg = 2.f / (1.f + __expf(-2.f * pre[2])) - 1.f;
            const float og = 1.f / (1.f + __expf(-pre[3]));
            c = fmaf(fg, c, ig * gg);
            const float tc = 2.f / (1.f + __expf(-2.f * c)) - 1.f;
            const float h  = og * tc;

            // ---- h -> ring slot (t+1)&3, hi/lo planes, paired dword stores ----
            // (overwrites h(t-3): safe, B2's group-wide >=t certificate means
            // every block finished step t-1 >= its read of slot (t-3)&3)
            const unsigned hh = f2bf(h);
            const unsigned hl = f2bf(h - bf2f(hh));
            const unsigned packed = hh | (hl << 16);
            const unsigned part = (unsigned)__shfl_xor((int)packed, 1, 64);
            if ((u & 1) == 0) {
                const unsigned sH = __builtin_amdgcn_perm(part, packed, 0x05040100u);
                const unsigned sL = __builtin_amdgcn_perm(part, packed, 0x07060302u);
                const int slot    = (t + 1) & 3;
                const int pairidx = (b2 * HH + ug) >> 1;
                if constexpr (FAST) {  // plain write-through -> XCD L2 (probed)
                    __hip_atomic_store(hb32 + (base_hi + slot) * (PLANE / 2) + pairidx, sH,
                                       __ATOMIC_RELAXED, __HIP_MEMORY_SCOPE_WORKGROUP);
                    __hip_atomic_store(hb32 + (base_lo + slot) * (PLANE / 2) + pairidx, sL,
                                       __ATOMIC_RELAXED, __HIP_MEMORY_SCOPE_WORKGROUP);
                } else {
                    __hip_atomic_store(hb32 + (base_hi + slot) * (PLANE / 2) + pairidx, sH,
                                       __ATOMIC_RELAXED, __HIP_MEMORY_SCOPE_AGENT);
                    __hip_atomic_store(hb32 + (base_lo + slot) * (PLANE / 2) + pairidx, sL,
                                       __ATOMIC_RELAXED, __HIP_MEMORY_SCOPE_AGENT);
                }
            }

            // y[b][t]: reduce 16 units, one atomic per (block, batch)
            float yp = h * wfc;
            yp += __shfl_down(yp, 8, 16);
            yp += __shfl_down(yp, 4, 16);
            yp += __shfl_down(yp, 2, 16);
            yp += __shfl_down(yp, 1, 16);
            if (u == 0) {
                if (ut == 0) yp += bfcv;
                if constexpr (FAST)  // L2-local add; line is group-exclusive
                    __hip_atomic_fetch_add(out + Y_OFF + bglob * TT + t, yp,
                                           __ATOMIC_RELAXED, __HIP_MEMORY_SCOPE_WORKGROUP);
                else
                    atomicAdd(out + Y_OFF + bglob * TT + t, yp);
            }
            if (t == TT - 1) {
                out[HN_OFF + bglob * HH + ug] = h;
                out[CN_OFF + bglob * HH + ug] = c;
            }
        }
        // B3: compiler emits s_waitcnt vmcnt(0) before s_barrier -> all h
        // stores are in L2 (FAST) / MALL (SLOW) before the counter bump.
        // Also fences GSP reuse (next step's per-wave writes) against this
        // step's epilogue reads. R0-proven release: drain -> barrier -> sc1.
        __syncthreads();
        if (tid == 0) st_agent(stepc + ut * CPAD, (unsigned)(t + 1));  // sc1 always
    }
}

__global__ __launch_bounds__(256, 1)
void lstm_xcd(const float* __restrict__ x, const float* __restrict__ Wih,
              const float* __restrict__ Whh, const float* __restrict__ bih,
              const float* __restrict__ bhh, const float* __restrict__ Wfc,
              const float* __restrict__ bfc, float* __restrict__ out,
              unsigned short* __restrict__ hb, unsigned* __restrict__ cnt)
{
    __shared__ int s_grp, s_ut, s_fast;
    __shared__ float gsp[4 * 4 * 16 * 20];  // 20 KB cross-wave partial-C

    const int tid = threadIdx.x;
    // cnt layout (uints, 32 KB): [0,4096) padded stepc (grp*512 + blk*16,
    // 64B per counter); [4096,4104) claim; [4136] bar1; probe data
    // 4608+g*32 (uint4); pflag 4864+g*32; v_ok 5120+g*32; v_tot 5376+g*32
    unsigned* claim = cnt + 4096;
    unsigned* bar1  = cnt + 4136;

    if (tid == 0) {
        unsigned xcc;
        asm volatile("s_getreg_b32 %0, hwreg(HW_REG_XCC_ID)" : "=s"(xcc));
        xcc &= 7u;
        const unsigned slot = add_agent(claim + xcc, 1u);
        asm volatile("s_waitcnt vmcnt(0)" ::: "memory");
        add_agent(bar1, 1u);
        while (ld_agent(bar1) < 256u) __builtin_amdgcn_s_sleep(1);
        bool pure = true;
        for (int g2 = 0; g2 < 8; ++g2) pure &= (ld_agent(claim + g2) == (unsigned)NBLK);

        int fast = 0, grp, ut;
        if (pure) {
            grp = (int)xcc; ut = (int)slot;
            // ---- coherence probe of the FAST data mechanism (all waits
            // terminate: pflag set unconditionally by ut0; votes reach 32
            // unconditionally)
            unsigned* probe = cnt + 4608 + grp * 32;
            unsigned* pflag = cnt + 4864 + grp * 32;
            unsigned* v_ok  = cnt + 5120 + grp * 32;
            unsigned* v_tot = cnt + 5376 + grp * 32;
            if (ut == 0) {
                uint4 m = make_uint4(0xC0FFEE42u, 0x5EED5EEDu, 0xA110C8EDu, 0xB16B00B5u);
                *(uint4*)probe = m;                      // plain write-through store
                asm volatile("s_waitcnt vmcnt(0)" ::: "memory");
                st_agent(pflag, 1u);
            }
            while (ld_agent(pflag) == 0u) __builtin_amdgcn_s_sleep(1);
            const uint4 d = ld_sc0_probe(probe);         // the FAST load path
            const unsigned ok = (d.x == 0xC0FFEE42u && d.y == 0x5EED5EEDu &&
                                 d.z == 0xA110C8EDu && d.w == 0xB16B00B5u) ? 1u : 0u;
            add_agent(v_ok, ok);
            asm volatile("s_waitcnt vmcnt(0)" ::: "memory");  // ok before total
            add_agent(v_tot, 1u);
            while (ld_agent(v_tot) < (unsigned)NBLK) __builtin_amdgcn_s_sleep(1);
            fast = (ld_agent(v_ok) == (unsigned)NBLK) ? 1 : 0;
        } else {
            grp = (int)(blockIdx.x >> 5); ut = (int)(blockIdx.x & 31);
        }
        s_grp = grp; s_ut = ut; s_fast = fast;
    }
    __syncthreads();
    const int grp = s_grp, ut = s_ut;
    unsigned* stepc = cnt + grp * (NBLK * CPAD);

    if (s_fast) run_loop<true >(x, Whh, Wih, bih, bhh, Wfc, bfc, out, hb, stepc, grp, ut, gsp);
    else        run_loop<false>(x, Whh, Wih, bih, bhh, Wfc, bfc, out, hb, stepc, grp, ut, gsp);
}

extern "C" void kernel_launch(void* const* d_in, const int* in_sizes, int n_in,
                              void* d_out, int out_size, void* d_ws, size_t ws_size,
                              hipStream_t stream) {
    const float* x   = (const float*)d_in[0];
    const float* Wih = (const float*)d_in[1];
    const float* Whh = (const float*)d_in[2];
    const float* bih = (const float*)d_in[3];
    const float* bhh = (const float*)d_in[4];
    const float* Wfc = (const float*)d_in[5];
    const float* bfc = (const float*)d_in[6];
    float* out = (float*)d_out;

    // ws: [0,32K) counters/claims/probe (padded); [32K, 32K+512K) h ring
    unsigned*       cnt = (unsigned*)d_ws;
    unsigned short* hb  = (unsigned short*)((char*)d_ws + 32768);

    hipMemsetAsync(d_ws, 0, 32768 + 8 * 2 * DEPTH * PLANE * sizeof(unsigned short), stream);
    hipMemsetAsync(d_out, 0, BB * TT * sizeof(float), stream);  // atomic target

    lstm_xcd<<<dim3(256), dim3(256), 0, stream>>>(
        x, Wih, Whh, bih, bhh, Wfc, bfc, out, hb, cnt);
}